// Round 3
// baseline (440.596 us; speedup 1.0000x reference)
//
#include <hip/hip_runtime.h>
#include <math.h>

// Problem constants (B=1)
#define SEQ    4096
#define DMODEL 512
#define NH     8
#define HDIM   64
#define KTOP   8
#define SM_SCALE 0.125f
#define NEGINF (-INFINITY)

// ---------------------------------------------------------------------------
// GEMM (NT): Out[M][512] = X[M][512] @ W[512][512]^T + bias, M=4096, N=512
// tile 64(M) x 128(N), K-step 16, 256 threads, 4x8 accum per lane.
// LDS transposed: Xs[k][m] stride 68; Ws[k][frag] with 8-float fragments at
// 12-float stride -> fragment bank = (cg*12)%32, 2-way only (free).
// blockIdx.z selects one of three (X,W,b,Out) sets (fused QKV projection).
// ---------------------------------------------------------------------------
__global__ __launch_bounds__(256) void gemm_nt(
    const float* __restrict__ X0, const float* __restrict__ W0,
    const float* __restrict__ B0, float* __restrict__ O0,
    const float* __restrict__ X1, const float* __restrict__ W1,
    const float* __restrict__ B1, float* __restrict__ O1,
    const float* __restrict__ X2, const float* __restrict__ W2,
    const float* __restrict__ B2, float* __restrict__ O2)
{
    const float *X, *W, *Bi;
    float *Out;
    if (blockIdx.z == 0)      { X = X0; W = W0; Bi = B0; Out = O0; }
    else if (blockIdx.z == 1) { X = X1; W = W1; Bi = B1; Out = O1; }
    else                      { X = X2; W = W2; Bi = B2; Out = O2; }

    __shared__ __align__(16) float Xs[16 * 68];    // [k][m]
    __shared__ __align__(16) float Ws[16 * 192];   // [k][(n>>3)*12 + (n&7)]

    const int tid   = threadIdx.x;
    const int mBase = blockIdx.x * 64;
    const int nBase = blockIdx.y * 128;
    const int cg = tid & 15, rg = tid >> 4;
    const int m0 = rg * 4;           // 4 output rows
    const int nfo = cg * 12;         // B fragment offset in LDS (8 cols)

    float acc[4][8] = {};

    for (int k0 = 0; k0 < DMODEL; k0 += 16) {
        // ---- stage A tile: 64 rows x 16 k = 256 float4, one round ----
        {
            int row = tid >> 2, kc = (tid & 3) << 2;
            float4 xv = *(const float4*)(X + (size_t)(mBase + row) * DMODEL + k0 + kc);
            Xs[(kc + 0) * 68 + row] = xv.x;
            Xs[(kc + 1) * 68 + row] = xv.y;
            Xs[(kc + 2) * 68 + row] = xv.z;
            Xs[(kc + 3) * 68 + row] = xv.w;
        }
        // ---- stage B tile: 128 rows x 16 k = 512 float4, two rounds ----
        #pragma unroll
        for (int r = 0; r < 2; ++r) {
            int i  = tid + r * 256;
            int n  = i >> 2, kc = (i & 3) << 2;
            float4 wv = *(const float4*)(W + (size_t)(nBase + n) * DMODEL + k0 + kc);
            int nb = (n >> 3) * 12 + (n & 7);
            Ws[(kc + 0) * 192 + nb] = wv.x;
            Ws[(kc + 1) * 192 + nb] = wv.y;
            Ws[(kc + 2) * 192 + nb] = wv.z;
            Ws[(kc + 3) * 192 + nb] = wv.w;
        }
        __syncthreads();

        #pragma unroll
        for (int kk = 0; kk < 16; ++kk) {
            float4 a  = *(const float4*)(Xs + kk * 68 + m0);
            float4 b0 = *(const float4*)(Ws + kk * 192 + nfo);
            float4 b1 = *(const float4*)(Ws + kk * 192 + nfo + 4);
            float av[4] = {a.x, a.y, a.z, a.w};
            float bv[8] = {b0.x, b0.y, b0.z, b0.w, b1.x, b1.y, b1.z, b1.w};
            #pragma unroll
            for (int i = 0; i < 4; ++i)
                #pragma unroll
                for (int j = 0; j < 8; ++j)
                    acc[i][j] = fmaf(av[i], bv[j], acc[i][j]);
        }
        __syncthreads();
    }

    const int nCol = nBase + cg * 8;
    float4 bq0 = *(const float4*)(Bi + nCol);
    float4 bq1 = *(const float4*)(Bi + nCol + 4);
    float bb[8] = {bq0.x, bq0.y, bq0.z, bq0.w, bq1.x, bq1.y, bq1.z, bq1.w};
    #pragma unroll
    for (int i = 0; i < 4; ++i) {
        float* op = Out + (size_t)(mBase + m0 + i) * DMODEL + nCol;
        float4 o0, o1;
        o0.x = acc[i][0] + bb[0]; o0.y = acc[i][1] + bb[1];
        o0.z = acc[i][2] + bb[2]; o0.w = acc[i][3] + bb[3];
        o1.x = acc[i][4] + bb[4]; o1.y = acc[i][5] + bb[5];
        o1.z = acc[i][6] + bb[6]; o1.w = acc[i][7] + bb[7];
        *(float4*)(op)     = o0;
        *(float4*)(op + 4) = o1;
    }
}

// ---------------------------------------------------------------------------
// Attention phase A: partial top-8 over half of a (head, q-tile)'s K-range.
// 1024 blocks, heavy-first: b -> item p=b>>1 (head=p&7, qt=63-(p>>3)), half=b&1.
// Half 0 covers K-tiles [0,(qt+1)>>1), half 1 covers [(qt+1)>>1, qt+1)
// (diagonal tile kt==qt is always in half 1; empty ranges write -inf).
// Per K tile: scores[64q][64k] via 4x4 f32 microkernel -> LDS (stride 73),
// then 4 threads/row maintain register top-8 (compare-only fast path).
// Output: per-row 8 (val,idx) partials to d_ws.
// ---------------------------------------------------------------------------
__global__ __launch_bounds__(256) void attn_score_topk(
    const float* __restrict__ Qb, const float* __restrict__ Kb,
    float* __restrict__ partV, int* __restrict__ partI)
{
    const int b    = blockIdx.x;        // 0..1023, heavy items first
    const int p    = b >> 1;            // 0..511
    const int half = b & 1;
    const int h    = p & 7;
    const int qt   = 63 - (p >> 3);
    const int qBase = qt * 64;
    const int t0 = half ? ((qt + 1) >> 1) : 0;
    const int t1 = half ? (qt + 1) : ((qt + 1) >> 1);
    const int tid  = threadIdx.x;

    __shared__ __align__(16) float Qs[64 * 68];   // Q^T  [d][q]
    __shared__ __align__(16) float Ks[64 * 68];   // K^T  [d][k]
    __shared__ __align__(16) float Ss[64 * 73];   // scores [q][k] / merge buffer

    // ---- stage Q block (transposed) ----
    #pragma unroll
    for (int it = 0; it < 4; ++it) {
        int i   = tid + it * 256;     // 1024 float4s
        int row = i >> 4;             // 16 float4 per 64-wide row
        int dc  = (i & 15) << 2;
        float4 v = *(const float4*)(Qb + (size_t)(qBase + row) * DMODEL + h * HDIM + dc);
        Qs[(dc + 0) * 68 + row] = v.x;
        Qs[(dc + 1) * 68 + row] = v.y;
        Qs[(dc + 2) * 68 + row] = v.z;
        Qs[(dc + 3) * 68 + row] = v.w;
    }

    const int cg = tid & 15, rg = tid >> 4;
    const int m0 = rg * 4, n0 = cg * 4;     // q rows / k cols of this lane

    // top-8 partial state: thread owns (row = tid&63, column part = tid>>6)
    const int prow = tid & 63, ppart = tid >> 6;
    float tv[KTOP];
    int   ti[KTOP];
    #pragma unroll
    for (int u = 0; u < KTOP; ++u) { tv[u] = NEGINF; ti[u] = 0; }
    float vmin = NEGINF;
    int   imin = 0;

    __syncthreads();

    for (int kt = t0; kt < t1; ++kt) {
        const int kBase = kt * 64;
        // ---- stage K tile (transposed) ----
        #pragma unroll
        for (int it = 0; it < 4; ++it) {
            int i   = tid + it * 256;
            int row = i >> 4;
            int dc  = (i & 15) << 2;
            float4 v = *(const float4*)(Kb + (size_t)(kBase + row) * DMODEL + h * HDIM + dc);
            Ks[(dc + 0) * 68 + row] = v.x;
            Ks[(dc + 1) * 68 + row] = v.y;
            Ks[(dc + 2) * 68 + row] = v.z;
            Ks[(dc + 3) * 68 + row] = v.w;
        }
        __syncthreads();

        // ---- phase 1: scores ----
        float acc[4][4] = {};
        #pragma unroll 8
        for (int kk = 0; kk < HDIM; ++kk) {
            float4 a = *(const float4*)(Qs + kk * 68 + m0);
            float4 b4 = *(const float4*)(Ks + kk * 68 + n0);
            float av[4] = {a.x, a.y, a.z, a.w};
            float bv[4] = {b4.x, b4.y, b4.z, b4.w};
            #pragma unroll
            for (int i = 0; i < 4; ++i)
                #pragma unroll
                for (int j = 0; j < 4; ++j)
                    acc[i][j] = fmaf(av[i], bv[j], acc[i][j]);
        }
        const bool diag = (kt == qt);
        #pragma unroll
        for (int i = 0; i < 4; ++i) {
            #pragma unroll
            for (int j = 0; j < 4; ++j) {
                float sv = acc[i][j] * SM_SCALE;
                if (diag && (kBase + n0 + j > qBase + m0 + i)) sv = NEGINF;
                Ss[(m0 + i) * 73 + (n0 + j)] = sv;
            }
        }
        __syncthreads();

        // ---- phase 2: top-8 scan (compare-only fast path) ----
        for (int j = 0; j < 16; ++j) {
            int   c = ppart * 16 + j;
            float v = Ss[prow * 73 + c];
            if (v > vmin) {
                tv[imin] = v;
                ti[imin] = kBase + c;
                vmin = tv[0]; imin = 0;
                #pragma unroll
                for (int u = 1; u < KTOP; ++u)
                    if (tv[u] < vmin) { vmin = tv[u]; imin = u; }
            }
        }
        __syncthreads();   // protects Ss & Ks for next iteration
    }

    // ---- merge 4 partial lists per row (reuse Ss as [64][33] val + idx) ----
    float* mV = Ss;
    int*   mI = (int*)(Ss + 64 * 33);
    #pragma unroll
    for (int u = 0; u < KTOP; ++u) {
        mV[prow * 33 + ppart * 8 + u] = tv[u];
        mI[prow * 33 + ppart * 8 + u] = ti[u];
    }
    __syncthreads();

    if (tid < 64) {
        float cv[32]; int ci[32];
        #pragma unroll
        for (int u = 0; u < 32; ++u) { cv[u] = mV[tid * 33 + u]; ci[u] = mI[tid * 33 + u]; }
        const int item2 = (((h << 6) | qt) << 1) | half;
        float* pv = partV + ((size_t)item2 * 64 + tid) * KTOP;
        int*   pi = partI + ((size_t)item2 * 64 + tid) * KTOP;
        for (int s = 0; s < KTOP; ++s) {
            int best = 0; float bvv = cv[0];
            #pragma unroll
            for (int u = 1; u < 32; ++u)
                if (cv[u] > bvv) { bvv = cv[u]; best = u; }
            pv[s] = bvv; pi[s] = ci[best]; cv[best] = NEGINF;
        }
    }
}

// ---------------------------------------------------------------------------
// Attention phase B: merge the 2 half-partials per row -> top-8, softmax,
// weighted V gather. 512 blocks = (head, qtile).
// ---------------------------------------------------------------------------
__global__ __launch_bounds__(256) void attn_merge_gather(
    const float* __restrict__ Vb, const float* __restrict__ partV,
    const int* __restrict__ partI, float* __restrict__ Ob)
{
    const int b  = blockIdx.x;     // 0..511
    const int h  = b & 7;
    const int qt = b >> 3;
    const int qBase = qt * 64;
    const int tid = threadIdx.x;

    __shared__ float smW[64 * KTOP];
    __shared__ int   smI[64 * KTOP];

    if (tid < 64) {
        const size_t base = (size_t)(((h << 6) | qt) << 1) * 64;
        float cv[16]; int ci[16];
        #pragma unroll
        for (int u = 0; u < KTOP; ++u) {
            cv[u]        = partV[(base + tid) * KTOP + u];
            ci[u]        = partI[(base + tid) * KTOP + u];
            cv[KTOP + u] = partV[(base + 64 + tid) * KTOP + u];
            ci[KTOP + u] = partI[(base + 64 + tid) * KTOP + u];
        }
        float w8[KTOP]; int i8[KTOP];
        for (int s = 0; s < KTOP; ++s) {
            int best = 0; float bvv = cv[0];
            #pragma unroll
            for (int u = 1; u < 16; ++u)
                if (cv[u] > bvv) { bvv = cv[u]; best = u; }
            w8[s] = bvv; i8[s] = ci[best]; cv[best] = NEGINF;
        }
        // softmax (w8[0] is the max; always finite: diagonal exists)
        float m = w8[0];
        float e[KTOP], Z = 0.f;
        #pragma unroll
        for (int s = 0; s < KTOP; ++s) { e[s] = expf(w8[s] - m); Z += e[s]; }
        float invZ = 1.0f / Z;
        #pragma unroll
        for (int s = 0; s < KTOP; ++s) {
            smW[tid * KTOP + s] = e[s] * invZ;
            smI[tid * KTOP + s] = i8[s];
        }
    }
    __syncthreads();

    // ---- weighted gather of V: 4 threads per row, 16 d each ----
    const int row = tid >> 2, dp = tid & 3;
    float w8[KTOP]; int i8[KTOP];
    #pragma unroll
    for (int s = 0; s < KTOP; ++s) { w8[s] = smW[row * KTOP + s]; i8[s] = smI[row * KTOP + s]; }
    float o[16];
    #pragma unroll
    for (int t = 0; t < 16; ++t) o[t] = 0.f;
    for (int s = 0; s < KTOP; ++s) {
        const float w = w8[s];
        const float* vp = Vb + (size_t)i8[s] * DMODEL + h * HDIM + dp * 16;
        #pragma unroll
        for (int t = 0; t < 4; ++t) {
            float4 v = *(const float4*)(vp + t * 4);
            o[t * 4 + 0] = fmaf(w, v.x, o[t * 4 + 0]);
            o[t * 4 + 1] = fmaf(w, v.y, o[t * 4 + 1]);
            o[t * 4 + 2] = fmaf(w, v.z, o[t * 4 + 2]);
            o[t * 4 + 3] = fmaf(w, v.w, o[t * 4 + 3]);
        }
    }
    float* op = Ob + (size_t)(qBase + row) * DMODEL + h * HDIM + dp * 16;
    #pragma unroll
    for (int t = 0; t < 4; ++t) {
        float4 v;
        v.x = o[t * 4 + 0]; v.y = o[t * 4 + 1];
        v.z = o[t * 4 + 2]; v.w = o[t * 4 + 3];
        *(float4*)(op + t * 4) = v;
    }
}

// ---------------------------------------------------------------------------
extern "C" void kernel_launch(void* const* d_in, const int* in_sizes, int n_in,
                              void* d_out, int out_size, void* d_ws, size_t ws_size,
                              hipStream_t stream)
{
    const float* h_query = (const float*)d_in[0];
    const float* h_kv    = (const float*)d_in[1];
    const float* Wq      = (const float*)d_in[2];
    const float* bq      = (const float*)d_in[3];
    const float* Wk      = (const float*)d_in[4];
    const float* bk      = (const float*)d_in[5];
    const float* Wv      = (const float*)d_in[6];
    const float* bv      = (const float*)d_in[7];
    const float* Wo      = (const float*)d_in[8];
    const float* bo      = (const float*)d_in[9];
    float* out = (float*)d_out;

    const size_t MAT = (size_t)SEQ * DMODEL;     // 2M floats
    float* ws = (float*)d_ws;
    float* Qb = ws;
    float* Kb = ws + MAT;
    float* Vb = ws + 2 * MAT;
    float* Ob = ws + 3 * MAT;
    float* partV = ws + 4 * MAT;                       // [1024][64][8] f32
    int*   partI = (int*)(ws + 4 * MAT + 1024 * 64 * KTOP);

    // fused QKV projections (z selects matrix)
    dim3 gQKV(SEQ / 64, DMODEL / 128, 3);
    gemm_nt<<<gQKV, 256, 0, stream>>>(h_query, Wq, bq, Qb,
                                      h_kv,    Wk, bk, Kb,
                                      h_kv,    Wv, bv, Vb);

    // causal attention + top-8: balanced half-items, then merge+gather
    attn_score_topk<<<dim3(1024), 256, 0, stream>>>(Qb, Kb, partV, partI);
    attn_merge_gather<<<dim3(512), 256, 0, stream>>>(Vb, partV, partI, Ob);

    // output projection
    dim3 gO(SEQ / 64, DMODEL / 128, 1);
    gemm_nt<<<gO, 256, 0, stream>>>(Ob, Wo, bo, out,
                                    Ob, Wo, bo, out,
                                    Ob, Wo, bo, out);
}

// Round 7
// 290.461 us; speedup vs baseline: 1.5169x; 1.5169x over previous
//
#include <hip/hip_runtime.h>
#include <math.h>

// Problem constants (B=1)
#define SEQ    4096
#define DMODEL 512
#define NH     8
#define HDIM   64
#define KTOP   8
#define SM_SCALE 0.125f
#define NEGINF (-INFINITY)

typedef short  bf16x8 __attribute__((ext_vector_type(8)));
typedef float  f32x4  __attribute__((ext_vector_type(4)));

#define MFMA(a,b,c) __builtin_amdgcn_mfma_f32_16x16x32_bf16((a),(b),(c),0,0,0)

__device__ __forceinline__ unsigned short bf16_rne(float x) {
    unsigned int b = __float_as_uint(x);
    return (unsigned short)((b + 0x7FFFu + ((b >> 16) & 1u)) >> 16);
}

// 3-way RNE split: x = h + m + l + eps, |eps| <= 2^-27 |x|
__device__ __forceinline__ void split3(float x, unsigned short &h,
                                       unsigned short &m, unsigned short &l) {
    unsigned int b  = __float_as_uint(x);
    unsigned int hb = (b + 0x7FFFu + ((b >> 16) & 1u)) & 0xFFFF0000u;
    h = (unsigned short)(hb >> 16);
    float r = x - __uint_as_float(hb);                 // exact
    unsigned int rb = __float_as_uint(r);
    unsigned int mb = (rb + 0x7FFFu + ((rb >> 16) & 1u)) & 0xFFFF0000u;
    m = (unsigned short)(mb >> 16);
    float r2 = r - __uint_as_float(mb);                // exact
    l = bf16_rne(r2);
}

// ---------------------------------------------------------------------------
// Pre-split the 4 weight matrices into h/m/l bf16. Layout [4][512][512] each.
// ---------------------------------------------------------------------------
__global__ __launch_bounds__(256) void prep_w(
    const float* __restrict__ Wq, const float* __restrict__ Wk,
    const float* __restrict__ Wv, const float* __restrict__ Wo,
    unsigned short* __restrict__ WH, unsigned short* __restrict__ WM,
    unsigned short* __restrict__ WL)
{
    int idx = blockIdx.x * 256 + threadIdx.x;      // 262144 float4s total
    int w   = idx >> 16;                           // 65536 float4 per W
    int sub = idx & 65535;
    const float* src = (w == 0) ? Wq : (w == 1) ? Wk : (w == 2) ? Wv : Wo;
    float4 v = *(const float4*)(src + (size_t)sub * 4);
    ushort4 hh, mm, ll;
    split3(v.x, hh.x, mm.x, ll.x); split3(v.y, hh.y, mm.y, ll.y);
    split3(v.z, hh.z, mm.z, ll.z); split3(v.w, hh.w, mm.w, ll.w);
    *(ushort4*)(WH + (size_t)idx * 4) = hh;
    *(ushort4*)(WM + (size_t)idx * 4) = mm;
    *(ushort4*)(WL + (size_t)idx * 4) = ll;
}

// ---------------------------------------------------------------------------
// Fused QKV projection GEMM, triple-split 6-product MFMA emulation.
// Tile 64(M)x128(N), K-step 32, 4 waves 2x2, 2x4 16x16x32 frags each.
// A (f32 X) split in-kernel; B (W) pre-split copies. LDS stride 40 ushort.
// Epilogue: z=0 -> Q split3 (SM_SCALE folded); z=1 -> K split3; z=2 -> V f32.
// ---------------------------------------------------------------------------
__global__ __launch_bounds__(256) void gemm_qkv(
    const float* __restrict__ Xq, const float* __restrict__ Xkv,
    const unsigned short* __restrict__ WH, const unsigned short* __restrict__ WM,
    const unsigned short* __restrict__ WL,
    const float* __restrict__ bq, const float* __restrict__ bk,
    const float* __restrict__ bv,
    unsigned short* __restrict__ Qh_, unsigned short* __restrict__ Qm_,
    unsigned short* __restrict__ Ql_,
    unsigned short* __restrict__ Kh_, unsigned short* __restrict__ Km_,
    unsigned short* __restrict__ Kl_,
    float* __restrict__ Vb)
{
    const int z = blockIdx.z;
    const float* X  = (z == 0) ? Xq : Xkv;
    const float* Bi = (z == 0) ? bq : (z == 1) ? bk : bv;
    const unsigned short* Wh_g = WH + (size_t)z * DMODEL * DMODEL;
    const unsigned short* Wm_g = WM + (size_t)z * DMODEL * DMODEL;
    const unsigned short* Wl_g = WL + (size_t)z * DMODEL * DMODEL;

    __shared__ unsigned short Xh[64 * 40], Xm[64 * 40], Xl[64 * 40];
    __shared__ unsigned short Wh[128 * 40], Wm[128 * 40], Wl[128 * 40];

    const int tid   = threadIdx.x;
    const int mBase = blockIdx.x * 64;
    const int nBase = blockIdx.y * 128;
    const int wave = tid >> 6, lane = tid & 63;
    const int l15 = lane & 15, l4 = lane >> 4;
    const int wr = (wave >> 1) * 32;
    const int wc = (wave & 1) * 64;

    const f32x4 z4 = {0.f, 0.f, 0.f, 0.f};
    f32x4 acc[2][4];
    #pragma unroll
    for (int mt = 0; mt < 2; ++mt)
        #pragma unroll
        for (int nt = 0; nt < 4; ++nt) acc[mt][nt] = z4;

    for (int k0 = 0; k0 < DMODEL; k0 += 32) {
        // stage A (f32 -> split3): 512 float4, 2/thread
        #pragma unroll
        for (int r = 0; r < 2; ++r) {
            int i = tid + r * 256;
            int row = i >> 3, c4 = (i & 7) * 4;
            float4 xv = *(const float4*)(X + (size_t)(mBase + row) * DMODEL + k0 + c4);
            ushort4 hh, mm, ll;
            split3(xv.x, hh.x, mm.x, ll.x); split3(xv.y, hh.y, mm.y, ll.y);
            split3(xv.z, hh.z, mm.z, ll.z); split3(xv.w, hh.w, mm.w, ll.w);
            *(ushort4*)&Xh[row * 40 + c4] = hh;
            *(ushort4*)&Xm[row * 40 + c4] = mm;
            *(ushort4*)&Xl[row * 40 + c4] = ll;
        }
        // stage B (pre-split copies): 3 levels x 512 uint4, 6/thread
        #pragma unroll
        for (int r = 0; r < 6; ++r) {
            const int lvl = r >> 1;                 // compile-time per r
            int i = tid + r * 256;
            int j = i & 511;
            int row = j >> 2, c8 = (j & 3) * 8;
            const unsigned short* s =
                (lvl == 0 ? Wh_g : lvl == 1 ? Wm_g : Wl_g) +
                (size_t)(nBase + row) * DMODEL + k0 + c8;
            uint4 v = *(const uint4*)s;
            unsigned short* d = (lvl == 0 ? Wh : lvl == 1 ? Wm : Wl);
            *(uint4*)(d + row * 40 + c8) = v;
        }
        __syncthreads();

        bf16x8 ah[2], am[2], al[2];
        #pragma unroll
        for (int mt = 0; mt < 2; ++mt) {
            ah[mt] = *(const bf16x8*)&Xh[(wr + mt * 16 + l15) * 40 + l4 * 8];
            am[mt] = *(const bf16x8*)&Xm[(wr + mt * 16 + l15) * 40 + l4 * 8];
            al[mt] = *(const bf16x8*)&Xl[(wr + mt * 16 + l15) * 40 + l4 * 8];
        }
        #pragma unroll
        for (int nt = 0; nt < 4; ++nt) {
            bf16x8 bh = *(const bf16x8*)&Wh[(wc + nt * 16 + l15) * 40 + l4 * 8];
            bf16x8 bm = *(const bf16x8*)&Wm[(wc + nt * 16 + l15) * 40 + l4 * 8];
            bf16x8 bl = *(const bf16x8*)&Wl[(wc + nt * 16 + l15) * 40 + l4 * 8];
            #pragma unroll
            for (int mt = 0; mt < 2; ++mt) {
                // small -> large accumulation
                acc[mt][nt] = MFMA(am[mt], bm, acc[mt][nt]);
                acc[mt][nt] = MFMA(ah[mt], bl, acc[mt][nt]);
                acc[mt][nt] = MFMA(al[mt], bh, acc[mt][nt]);
                acc[mt][nt] = MFMA(ah[mt], bm, acc[mt][nt]);
                acc[mt][nt] = MFMA(am[mt], bh, acc[mt][nt]);
                acc[mt][nt] = MFMA(ah[mt], bh, acc[mt][nt]);
            }
        }
        __syncthreads();
    }

    #pragma unroll
    for (int nt = 0; nt < 4; ++nt) {
        const int col = nBase + wc + nt * 16 + l15;
        const float bias = Bi[col];
        #pragma unroll
        for (int mt = 0; mt < 2; ++mt) {
            #pragma unroll
            for (int r = 0; r < 4; ++r) {
                int row = mBase + wr + mt * 16 + l4 * 4 + r;
                float v = acc[mt][nt][r] + bias;
                size_t o = (size_t)row * DMODEL + col;
                if (z == 2) {
                    Vb[o] = v;
                } else {
                    if (z == 0) v *= SM_SCALE;
                    unsigned short h_, m_, l_;
                    split3(v, h_, m_, l_);
                    if (z == 0) { Qh_[o] = h_; Qm_[o] = m_; Ql_[o] = l_; }
                    else        { Kh_[o] = h_; Km_[o] = m_; Kl_[o] = l_; }
                }
            }
        }
    }
}

// ---------------------------------------------------------------------------
// Output projection GEMM: pre-split A (Ob) and B (Wo), f32 out + bias.
// ---------------------------------------------------------------------------
__global__ __launch_bounds__(256) void gemm_o(
    const unsigned short* __restrict__ Ah_g, const unsigned short* __restrict__ Am_g,
    const unsigned short* __restrict__ Al_g,
    const unsigned short* __restrict__ Wh_g, const unsigned short* __restrict__ Wm_g,
    const unsigned short* __restrict__ Wl_g,
    const float* __restrict__ bo, float* __restrict__ Out)
{
    __shared__ unsigned short Xh[64 * 40], Xm[64 * 40], Xl[64 * 40];
    __shared__ unsigned short Wh[128 * 40], Wm[128 * 40], Wl[128 * 40];

    const int tid   = threadIdx.x;
    const int mBase = blockIdx.x * 64;
    const int nBase = blockIdx.y * 128;
    const int wave = tid >> 6, lane = tid & 63;
    const int l15 = lane & 15, l4 = lane >> 4;
    const int wr = (wave >> 1) * 32;
    const int wc = (wave & 1) * 64;

    const f32x4 z4 = {0.f, 0.f, 0.f, 0.f};
    f32x4 acc[2][4];
    #pragma unroll
    for (int mt = 0; mt < 2; ++mt)
        #pragma unroll
        for (int nt = 0; nt < 4; ++nt) acc[mt][nt] = z4;

    for (int k0 = 0; k0 < DMODEL; k0 += 32) {
        // stage A: 3 levels x 256 uint4, 3/thread
        #pragma unroll
        for (int r = 0; r < 3; ++r) {
            int row = tid >> 2, c8 = (tid & 3) * 8;
            const unsigned short* s =
                (r == 0 ? Ah_g : r == 1 ? Am_g : Al_g) +
                (size_t)(mBase + row) * DMODEL + k0 + c8;
            uint4 v = *(const uint4*)s;
            unsigned short* d = (r == 0 ? Xh : r == 1 ? Xm : Xl);
            *(uint4*)(d + row * 40 + c8) = v;
        }
        // stage B: 3 levels x 512 uint4, 6/thread
        #pragma unroll
        for (int r = 0; r < 6; ++r) {
            const int lvl = r >> 1;
            int i = tid + r * 256;
            int j = i & 511;
            int row = j >> 2, c8 = (j & 3) * 8;
            const unsigned short* s =
                (lvl == 0 ? Wh_g : lvl == 1 ? Wm_g : Wl_g) +
                (size_t)(nBase + row) * DMODEL + k0 + c8;
            uint4 v = *(const uint4*)s;
            unsigned short* d = (lvl == 0 ? Wh : lvl == 1 ? Wm : Wl);
            *(uint4*)(d + row * 40 + c8) = v;
        }
        __syncthreads();

        bf16x8 ah[2], am[2], al[2];
        #pragma unroll
        for (int mt = 0; mt < 2; ++mt) {
            ah[mt] = *(const bf16x8*)&Xh[(wr + mt * 16 + l15) * 40 + l4 * 8];
            am[mt] = *(const bf16x8*)&Xm[(wr + mt * 16 + l15) * 40 + l4 * 8];
            al[mt] = *(const bf16x8*)&Xl[(wr + mt * 16 + l15) * 40 + l4 * 8];
        }
        #pragma unroll
        for (int nt = 0; nt < 4; ++nt) {
            bf16x8 bh = *(const bf16x8*)&Wh[(wc + nt * 16 + l15) * 40 + l4 * 8];
            bf16x8 bm = *(const bf16x8*)&Wm[(wc + nt * 16 + l15) * 40 + l4 * 8];
            bf16x8 bl = *(const bf16x8*)&Wl[(wc + nt * 16 + l15) * 40 + l4 * 8];
            #pragma unroll
            for (int mt = 0; mt < 2; ++mt) {
                acc[mt][nt] = MFMA(am[mt], bm, acc[mt][nt]);
                acc[mt][nt] = MFMA(ah[mt], bl, acc[mt][nt]);
                acc[mt][nt] = MFMA(al[mt], bh, acc[mt][nt]);
                acc[mt][nt] = MFMA(ah[mt], bm, acc[mt][nt]);
                acc[mt][nt] = MFMA(am[mt], bh, acc[mt][nt]);
                acc[mt][nt] = MFMA(ah[mt], bh, acc[mt][nt]);
            }
        }
        __syncthreads();
    }

    #pragma unroll
    for (int nt = 0; nt < 4; ++nt) {
        const int col = nBase + wc + nt * 16 + l15;
        const float bias = bo[col];
        #pragma unroll
        for (int mt = 0; mt < 2; ++mt) {
            #pragma unroll
            for (int r = 0; r < 4; ++r) {
                int row = mBase + wr + mt * 16 + l4 * 4 + r;
                Out[(size_t)row * DMODEL + col] = acc[mt][nt][r] + bias;
            }
        }
    }
}

// ---------------------------------------------------------------------------
// Attention phase A (triple-split MFMA): partial top-8 over half a K-range.
// 1024 blocks: h=b&7 (XCD L2 locality), half=(b>>3)&1, qt=63-(b>>4).
// Q staged through the K LDS buffers -> registers (LDS = 3 K-bufs + Ss only).
// ---------------------------------------------------------------------------
__global__ __launch_bounds__(256) void attn_score_topk(
    const unsigned short* __restrict__ Qh_g, const unsigned short* __restrict__ Qm_g,
    const unsigned short* __restrict__ Ql_g,
    const unsigned short* __restrict__ Kh_g, const unsigned short* __restrict__ Km_g,
    const unsigned short* __restrict__ Kl_g,
    float* __restrict__ partV, int* __restrict__ partI)
{
    const int b    = blockIdx.x;        // 0..1023
    const int h    = b & 7;
    const int half = (b >> 3) & 1;
    const int qt   = 63 - (b >> 4);
    const int qBase = qt * 64;
    const int t0 = half ? ((qt + 1) >> 1) : 0;
    const int t1 = half ? (qt + 1) : ((qt + 1) >> 1);
    const int tid = threadIdx.x;

    __shared__ unsigned short Kh[64 * 68], Km[64 * 68], Kl[64 * 68];
    __shared__ float Ss[64 * 73];

    const int wave = tid >> 6, lane = tid & 63;
    const int l15 = lane & 15, l4 = lane >> 4;
    const int qoff = (wave & 1) * 32, koff = (wave >> 1) * 32;

    // ---- stage Q through the K buffers (3 levels x 512 uint4, 6/thread)
    #pragma unroll
    for (int r = 0; r < 6; ++r) {
        const int lvl = r >> 1;
        int i = tid + r * 256;
        int j = i & 511;
        int row = j >> 3, c8 = (j & 7) * 8;
        const unsigned short* s =
            (lvl == 0 ? Qh_g : lvl == 1 ? Qm_g : Ql_g) +
            (size_t)(qBase + row) * DMODEL + h * HDIM + c8;
        uint4 v = *(const uint4*)s;
        unsigned short* d = (lvl == 0 ? Kh : lvl == 1 ? Km : Kl);
        *(uint4*)(d + row * 68 + c8) = v;
    }
    __syncthreads();

    // hoist Q fragments to registers
    bf16x8 qh[2][2], qm[2][2], ql[2][2];
    #pragma unroll
    for (int mt = 0; mt < 2; ++mt)
        #pragma unroll
        for (int ks = 0; ks < 2; ++ks) {
            int o = (qoff + mt * 16 + l15) * 68 + ks * 32 + l4 * 8;
            qh[mt][ks] = *(const bf16x8*)&Kh[o];
            qm[mt][ks] = *(const bf16x8*)&Km[o];
            ql[mt][ks] = *(const bf16x8*)&Kl[o];
        }
    __syncthreads();   // Q reads done before K staging overwrites

    // top-8 partial state
    const int prow = tid & 63, ppart = tid >> 6;
    float tv[KTOP];
    int   ti[KTOP];
    #pragma unroll
    for (int u = 0; u < KTOP; ++u) { tv[u] = NEGINF; ti[u] = 0; }
    float vmin = NEGINF;
    int   imin = 0;

    const f32x4 z4 = {0.f, 0.f, 0.f, 0.f};

    for (int kt = t0; kt < t1; ++kt) {
        const int kBase = kt * 64;
        // ---- stage K tile (3 levels, pure copies)
        #pragma unroll
        for (int r = 0; r < 6; ++r) {
            const int lvl = r >> 1;
            int i = tid + r * 256;
            int j = i & 511;
            int row = j >> 3, c8 = (j & 7) * 8;
            const unsigned short* s =
                (lvl == 0 ? Kh_g : lvl == 1 ? Km_g : Kl_g) +
                (size_t)(kBase + row) * DMODEL + h * HDIM + c8;
            uint4 v = *(const uint4*)s;
            unsigned short* d = (lvl == 0 ? Kh : lvl == 1 ? Km : Kl);
            *(uint4*)(d + row * 68 + c8) = v;
        }
        __syncthreads();   // staging done AND previous scan done

        // ---- scores via 6-product MFMA
        f32x4 acc[2][2];
        acc[0][0] = z4; acc[0][1] = z4; acc[1][0] = z4; acc[1][1] = z4;
        #pragma unroll
        for (int nt = 0; nt < 2; ++nt) {
            #pragma unroll
            for (int ks = 0; ks < 2; ++ks) {
                int o = (koff + nt * 16 + l15) * 68 + ks * 32 + l4 * 8;
                bf16x8 kh = *(const bf16x8*)&Kh[o];
                bf16x8 km = *(const bf16x8*)&Km[o];
                bf16x8 kl = *(const bf16x8*)&Kl[o];
                #pragma unroll
                for (int mt = 0; mt < 2; ++mt) {
                    acc[mt][nt] = MFMA(qm[mt][ks], km, acc[mt][nt]);
                    acc[mt][nt] = MFMA(qh[mt][ks], kl, acc[mt][nt]);
                    acc[mt][nt] = MFMA(ql[mt][ks], kh, acc[mt][nt]);
                    acc[mt][nt] = MFMA(qh[mt][ks], km, acc[mt][nt]);
                    acc[mt][nt] = MFMA(qm[mt][ks], kh, acc[mt][nt]);
                    acc[mt][nt] = MFMA(qh[mt][ks], kh, acc[mt][nt]);
                }
            }
        }
        // ---- store with causal mask
        const bool diag = (kt == qt);
        #pragma unroll
        for (int mt = 0; mt < 2; ++mt) {
            #pragma unroll
            for (int nt = 0; nt < 2; ++nt) {
                #pragma unroll
                for (int r = 0; r < 4; ++r) {
                    int q  = qoff + mt * 16 + l4 * 4 + r;
                    int kc = koff + nt * 16 + l15;
                    float sv = acc[mt][nt][r];
                    if (diag && kc > q) sv = NEGINF;
                    Ss[q * 73 + kc] = sv;
                }
            }
        }
        __syncthreads();   // Ss ready; K reads done before next staging

        // ---- top-8 scan (compare-only fast path)
        for (int j = 0; j < 16; ++j) {
            int   c = ppart * 16 + j;
            float v = Ss[prow * 73 + c];
            if (v > vmin) {
                tv[imin] = v;
                ti[imin] = kBase + c;
                vmin = tv[0]; imin = 0;
                #pragma unroll
                for (int u = 1; u < KTOP; ++u)
                    if (tv[u] < vmin) { vmin = tv[u]; imin = u; }
            }
        }
        // next iteration's post-stage barrier orders scan reads vs Ss re-store
    }
    __syncthreads();   // last scan done before Ss reuse as merge buffer

    // ---- merge 4 partial lists per row (Ss as [64][33] val + [64][33] idx)
    float* mV = Ss;
    int*   mI = (int*)(Ss + 64 * 33);
    #pragma unroll
    for (int u = 0; u < KTOP; ++u) {
        mV[prow * 33 + ppart * 8 + u] = tv[u];
        mI[prow * 33 + ppart * 8 + u] = ti[u];
    }
    __syncthreads();

    if (tid < 64) {
        float cv[32]; int ci[32];
        #pragma unroll
        for (int u = 0; u < 32; ++u) { cv[u] = mV[tid * 33 + u]; ci[u] = mI[tid * 33 + u]; }
        const int item2 = (((h << 6) | qt) << 1) | half;
        float* pv = partV + ((size_t)item2 * 64 + tid) * KTOP;
        int*   pi = partI + ((size_t)item2 * 64 + tid) * KTOP;
        for (int s = 0; s < KTOP; ++s) {
            int best = 0; float bvv = cv[0];
            #pragma unroll
            for (int u = 1; u < 32; ++u)
                if (cv[u] > bvv) { bvv = cv[u]; best = u; }
            pv[s] = bvv; pi[s] = ci[best]; cv[best] = NEGINF;
        }
    }
}

// ---------------------------------------------------------------------------
// Attention phase B: merge 2 half-partials -> top-8, softmax, V gather.
// Output written split3 for the O-GEMM.
// ---------------------------------------------------------------------------
__global__ __launch_bounds__(256) void attn_merge_gather(
    const float* __restrict__ Vb, const float* __restrict__ partV,
    const int* __restrict__ partI,
    unsigned short* __restrict__ Obh, unsigned short* __restrict__ Obm,
    unsigned short* __restrict__ Obl)
{
    const int b  = blockIdx.x;     // 0..511
    const int h  = b & 7;
    const int qt = b >> 3;
    const int qBase = qt * 64;
    const int tid = threadIdx.x;

    __shared__ float smW[64 * KTOP];
    __shared__ int   smI[64 * KTOP];

    if (tid < 64) {
        const size_t base = (size_t)(((h << 6) | qt) << 1) * 64;
        float cv[16]; int ci[16];
        #pragma unroll
        for (int u = 0; u < KTOP; ++u) {
            cv[u]        = partV[(base + tid) * KTOP + u];
            ci[u]        = partI[(base + tid) * KTOP + u];
            cv[KTOP + u] = partV[(base + 64 + tid) * KTOP + u];
            ci[KTOP + u] = partI[(base + 64 + tid) * KTOP + u];
        }
        float w8[KTOP]; int i8[KTOP];
        for (int s = 0; s < KTOP; ++s) {
            int best = 0; float bvv = cv[0];
            #pragma unroll
            for (int u = 1; u < 16; ++u)
                if (cv[u] > bvv) { bvv = cv[u]; best = u; }
            w8[s] = bvv; i8[s] = ci[best]; cv[best] = NEGINF;
        }
        float m = w8[0];
        float e[KTOP], Z = 0.f;
        #pragma unroll
        for (int s = 0; s < KTOP; ++s) { e[s] = expf(w8[s] - m); Z += e[s]; }
        float invZ = 1.0f / Z;
        #pragma unroll
        for (int s = 0; s < KTOP; ++s) {
            smW[tid * KTOP + s] = e[s] * invZ;
            smI[tid * KTOP + s] = i8[s];
        }
    }
    __syncthreads();

    const int row = tid >> 2, dp = tid & 3;
    float w8[KTOP]; int i8[KTOP];
    #pragma unroll
    for (int s = 0; s < KTOP; ++s) { w8[s] = smW[row * KTOP + s]; i8[s] = smI[row * KTOP + s]; }
    float o[16];
    #pragma unroll
    for (int t = 0; t < 16; ++t) o[t] = 0.f;
    for (int s = 0; s < KTOP; ++s) {
        const float w = w8[s];
        const float* vp = Vb + (size_t)i8[s] * DMODEL + h * HDIM + dp * 16;
        #pragma unroll
        for (int t = 0; t < 4; ++t) {
            float4 v = *(const float4*)(vp + t * 4);
            o[t * 4 + 0] = fmaf(w, v.x, o[t * 4 + 0]);
            o[t * 4 + 1] = fmaf(w, v.y, o[t * 4 + 1]);
            o[t * 4 + 2] = fmaf(w, v.z, o[t * 4 + 2]);
            o[t * 4 + 3] = fmaf(w, v.w, o[t * 4 + 3]);
        }
    }
    size_t op = (size_t)(qBase + row) * DMODEL + h * HDIM + dp * 16;
    #pragma unroll
    for (int t = 0; t < 4; ++t) {
        ushort4 hh, mm, ll;
        split3(o[t * 4 + 0], hh.x, mm.x, ll.x);
        split3(o[t * 4 + 1], hh.y, mm.y, ll.y);
        split3(o[t * 4 + 2], hh.z, mm.z, ll.z);
        split3(o[t * 4 + 3], hh.w, mm.w, ll.w);
        *(ushort4*)(Obh + op + t * 4) = hh;
        *(ushort4*)(Obm + op + t * 4) = mm;
        *(ushort4*)(Obl + op + t * 4) = ll;
    }
}

// ---------------------------------------------------------------------------
extern "C" void kernel_launch(void* const* d_in, const int* in_sizes, int n_in,
                              void* d_out, int out_size, void* d_ws, size_t ws_size,
                              hipStream_t stream)
{
    const float* h_query = (const float*)d_in[0];
    const float* h_kv    = (const float*)d_in[1];
    const float* Wq      = (const float*)d_in[2];
    const float* bq      = (const float*)d_in[3];
    const float* Wk      = (const float*)d_in[4];
    const float* bk      = (const float*)d_in[5];
    const float* Wv      = (const float*)d_in[6];
    const float* bv      = (const float*)d_in[7];
    const float* Wo      = (const float*)d_in[8];
    const float* bo      = (const float*)d_in[9];
    float* out = (float*)d_out;

    unsigned char* w = (unsigned char*)d_ws;
    const size_t MB = 1024 * 1024;
    unsigned short* WH  = (unsigned short*)(w);            // 2MB (4 matrices)
    unsigned short* WM  = (unsigned short*)(w + 2  * MB);  // 2MB
    unsigned short* WL  = (unsigned short*)(w + 4  * MB);  // 2MB
    unsigned short* Qh  = (unsigned short*)(w + 6  * MB);  // 4MB each
    unsigned short* Qm  = (unsigned short*)(w + 10 * MB);
    unsigned short* Ql  = (unsigned short*)(w + 14 * MB);
    unsigned short* Kh  = (unsigned short*)(w + 18 * MB);
    unsigned short* Km  = (unsigned short*)(w + 22 * MB);
    unsigned short* Kl  = (unsigned short*)(w + 26 * MB);
    unsigned short* Obh = (unsigned short*)(w + 30 * MB);
    unsigned short* Obm = (unsigned short*)(w + 34 * MB);
    unsigned short* Obl = (unsigned short*)(w + 38 * MB);
    float*          Vb  = (float*)        (w + 42 * MB);   // 8MB
    float*        partV = (float*)        (w + 50 * MB);   // 2MB
    int*          partI = (int*)          (w + 52 * MB);   // 2MB -> 54MB total
    (void)ws_size;

    prep_w<<<dim3(1024), 256, 0, stream>>>(Wq, Wk, Wv, Wo, WH, WM, WL);

    gemm_qkv<<<dim3(SEQ / 64, DMODEL / 128, 3), 256, 0, stream>>>(
        h_query, h_kv, WH, WM, WL, bq, bk, bv,
        Qh, Qm, Ql, Kh, Km, Kl, Vb);

    attn_score_topk<<<dim3(1024), 256, 0, stream>>>(
        Qh, Qm, Ql, Kh, Km, Kl, partV, partI);
    attn_merge_gather<<<dim3(512), 256, 0, stream>>>(
        Vb, partV, partI, Obh, Obm, Obl);

    const size_t WOFF = (size_t)3 * DMODEL * DMODEL;
    gemm_o<<<dim3(SEQ / 64, DMODEL / 128), 256, 0, stream>>>(
        Obh, Obm, Obl, WH + WOFF, WM + WOFF, WL + WOFF, bo, out);
}